// Round 8
// baseline (987.680 us; speedup 1.0000x reference)
//
#include <hip/hip_runtime.h>
#include <hip/hip_bf16.h>
#include <math.h>

#define N_NODES   100000
#define N_EDGES   2000000
#define N_GRAPHS  2000
#define IN_DIM    7
#define EDGE_DIM  4
#define HID       32
#define N_CLASSES 2
#define NEG_SLOPE 0.2f
#define BN_EPS    1e-5f
#define SCAN_B    1024

__device__ __forceinline__ unsigned bfbits(float f) {   // fp32 -> bf16 bits (RNE)
    unsigned u = __float_as_uint(f);
    return (u + 0x7FFFu + ((u >> 16) & 1u)) >> 16;
}

// ce3[l*4+d] = sum_k We_l[d][k] * a_edge_l[k]; also zero BN accumulators.
__global__ void k_ce_all(const float* __restrict__ lin_edge, const float* __restrict__ att_edge,
                         float* __restrict__ ce3, float* __restrict__ gsum3,
                         float* __restrict__ gsq3) {
    int t = threadIdx.x;
    if (t < 12) {
        int l = t >> 2, d = t & 3;
        float s = 0.f;
        for (int k = 0; k < HID; ++k)
            s += lin_edge[(size_t)l * EDGE_DIM * HID + d * HID + k] * att_edge[l * HID + k];
        ce3[t] = s;
    }
    if (t < 3 * HID) { gsum3[t] = 0.f; gsq3[t] = 0.f; }
}

__global__ void k_hist(const int* __restrict__ dst, int* __restrict__ deg) {
    int e = blockIdx.x * blockDim.x + threadIdx.x;
    if (e < N_EDGES) atomicAdd(deg + dst[e], 1);
}

// ---- 3-phase multi-block exclusive scan of deg -> offs (+ cursor copy) ----
__global__ void k_scan1(const int* __restrict__ deg, int* __restrict__ offs,
                        int* __restrict__ bsum) {
    __shared__ int wsum[16];
    int t = threadIdx.x, lane = t & 63, w = t >> 6;
    int i = blockIdx.x * SCAN_B + t;
    int v = (i < N_NODES) ? deg[i] : 0;
    int x = v;
#pragma unroll
    for (int o = 1; o < 64; o <<= 1) { int y = __shfl_up(x, o, 64); if (lane >= o) x += y; }
    if (lane == 63) wsum[w] = x;
    __syncthreads();
    if (t < 16) {
        int s = wsum[t];
#pragma unroll
        for (int o = 1; o < 16; o <<= 1) { int y = __shfl_up(s, o, 16); if (t >= o) s += y; }
        wsum[t] = s;
    }
    __syncthreads();
    int excl = (w ? wsum[w - 1] : 0) + x - v;
    if (i < N_NODES) offs[i] = excl;
    if (t == 0) bsum[blockIdx.x] = wsum[15];
}

__global__ void k_scan2(int* __restrict__ bsum, int nb) {
    __shared__ int w0;
    int t = threadIdx.x, lane = t & 63, w = t >> 6;
    int v = (t < nb) ? bsum[t] : 0;
    int x = v;
#pragma unroll
    for (int o = 1; o < 64; o <<= 1) { int y = __shfl_up(x, o, 64); if (lane >= o) x += y; }
    if (w == 0 && lane == 63) w0 = x;
    __syncthreads();
    int excl = x - v + (w ? w0 : 0);
    if (t < nb) bsum[t] = excl;
}

__global__ void k_scan3(int* __restrict__ offs, const int* __restrict__ bsum,
                        int* __restrict__ cursor) {
    int i = blockIdx.x * SCAN_B + threadIdx.x;
    if (i < N_NODES) {
        int o = offs[i] + bsum[blockIdx.x];
        offs[i] = o;
        cursor[i] = o;
    }
}

// CSR scatter: pack[pos] = {src, dst, bf16(e0)|bf16(e1)<<16, bf16(e2)}.
__global__ void k_scatter(const int* __restrict__ src, const int* __restrict__ dst,
                          const float4* __restrict__ eattr, const float* __restrict__ ce3,
                          int* __restrict__ cursor, int4* __restrict__ pack) {
    int e = blockIdx.x * blockDim.x + threadIdx.x;
    if (e >= N_EDGES) return;
    float4 ea = eattr[e];
    float e0 = ea.x * ce3[0] + ea.y * ce3[1] + ea.z * ce3[2] + ea.w * ce3[3];
    float e1 = ea.x * ce3[4] + ea.y * ce3[5] + ea.z * ce3[6] + ea.w * ce3[7];
    float e2 = ea.x * ce3[8] + ea.y * ce3[9] + ea.z * ce3[10] + ea.w * ce3[11];
    int d = dst[e];
    int pos = atomicAdd(cursor + d, 1);
    pack[pos] = make_int4(src[e], d,
                          (int)(bfbits(e0) | (bfbits(e1) << 16)),
                          (int)bfbits(e2));
}

// h(bf16) = act(in) @ W ; asrc = h.a_src ; adst = h.a_dst (fp32 math, bf16 h storage).
// BN+relu of previous layer fused when BN. 32 lanes per node, 8 nodes per block.
template <int INDIM, bool BN>
__global__ void k_linear(const float* __restrict__ in, const float* __restrict__ W,
                         const float* __restrict__ a_src, const float* __restrict__ a_dst,
                         const float* __restrict__ gsum, const float* __restrict__ gsq,
                         const float* __restrict__ gamma, const float* __restrict__ beta,
                         __hip_bfloat16* __restrict__ h, float* __restrict__ asrc,
                         float* __restrict__ adst) {
    __shared__ float Ws[INDIM * HID];
    for (int i = threadIdx.x; i < INDIM * HID; i += blockDim.x) Ws[i] = W[i];
    __syncthreads();
    int g = threadIdx.x >> 5, k = threadIdx.x & 31;
    int n = blockIdx.x * 8 + g;
    if (n >= N_NODES) return;
    float xv;
    if (BN) {
        const float invN = 1.f / (float)N_NODES;
        float mu = gsum[k] * invN;
        float var = gsq[k] * invN - mu * mu;
        var = fmaxf(var, 0.f);
        float scl = rsqrtf(var + BN_EPS) * gamma[k];
        float v = (in[(size_t)n * INDIM + k] - mu) * scl + beta[k];
        xv = fmaxf(v, 0.f);
    } else {
        xv = (k < INDIM) ? in[(size_t)n * INDIM + k] : 0.f;
    }
    float acc = 0.f;
#pragma unroll
    for (int d = 0; d < INDIM; ++d) acc += __shfl(xv, d, 32) * Ws[d * HID + k];
    h[(size_t)n * HID + k] = __float2bfloat16(acc);
    float vs = acc * a_src[k];
    float vd = acc * a_dst[k];
#pragma unroll
    for (int m = 16; m > 0; m >>= 1) {
        vs += __shfl_xor(vs, m, 32);
        vd += __shfl_xor(vd, m, 32);
    }
    if (k == 0) { asrc[n] = vs; adst[n] = vd; }
}

// Edge-parallel full-weight precompute: rec[e] = {src, w = exp(leaky(asrc+adst+edot))}.
// Scores are O(1) (inputs ~N(0,1), weights x0.1): exp without max-subtraction equals the
// reference segment-softmax algebraically (exp(s-m)/sum == exp(s)/sum), numerically safe.
template <int L>
__global__ void k_edgew(const int4* __restrict__ pack, const float* __restrict__ asrc,
                        const float* __restrict__ adst, int2* __restrict__ rec) {
    int e = blockIdx.x * blockDim.x + threadIdx.x;
    if (e >= N_EDGES) return;
    int4 pk = pack[e];
    unsigned z = (unsigned)pk.z;
    float edot;
    if (L == 0)      edot = __uint_as_float((z & 0xFFFFu) << 16);
    else if (L == 1) edot = __uint_as_float(z & 0xFFFF0000u);
    else             edot = __uint_as_float(((unsigned)pk.w & 0xFFFFu) << 16);
    float sc = asrc[pk.x] + adst[pk.y] + edot;
    sc = fmaxf(sc, NEG_SLOPE * sc);       // leaky-relu (slope<1)
    float w = __expf(sc);
    rec[e] = make_int2(pk.x, __float_as_int(w));
}

// Per-node weighted-sum aggregation. 32 lanes/node, 8 nodes/block.
// Lane split: sub = lane>>4 (edge-slot parity), c2 = lane&15 (channel pair 2c2,2c2+1).
// Per 8-edge batch: 4 int2 rec loads + 4 uint h loads (2 bf16 ch x 2 edges per inst)
// -> 1 memory instruction per edge, no exp/leaky in the loop.
__global__ void k_aggr(const int2* __restrict__ rec, const int* __restrict__ offs,
                       const int* __restrict__ endp, const __hip_bfloat16* __restrict__ hb,
                       const float* __restrict__ bias, float* __restrict__ out,
                       float* __restrict__ gsum, float* __restrict__ gsq) {
    __shared__ float ssum[HID], ssq[HID];
    if (threadIdx.x < HID) { ssum[threadIdx.x] = 0.f; ssq[threadIdx.x] = 0.f; }
    __syncthreads();
    int g = threadIdx.x >> 5;
    int lane = threadIdx.x & 31;
    int sub = lane >> 4;      // which edge of a slot pair
    int c2 = lane & 15;       // channel pair index
    int n = blockIdx.x * 8 + g;
    if (n < N_NODES) {
        int pbeg = offs[n], en = endp[n];
        float den = 0.f, a0 = 0.f, a1 = 0.f;
        for (int p = pbeg; p < en; p += 8) {
            int2 rc[4];
            unsigned hw[4];
#pragma unroll
            for (int m = 0; m < 4; ++m) {
                int q = p + 2 * m + sub;
                q = q < en ? q : en - 1;   // clamp; weight masked below
                rc[m] = rec[q];
            }
#pragma unroll
            for (int m = 0; m < 4; ++m)
                hw[m] = *(const unsigned*)(hb + (size_t)rc[m].x * HID + 2 * c2);
#pragma unroll
            for (int m = 0; m < 4; ++m) {
                float w = (p + 2 * m + sub < en) ? __int_as_float(rc[m].y) : 0.f;
                den += w;
                float lo = __uint_as_float((hw[m] & 0xFFFFu) << 16);
                float hi = __uint_as_float(hw[m] & 0xFFFF0000u);
                a0 = fmaf(w, lo, a0);
                a1 = fmaf(w, hi, a1);
            }
        }
        // combine the two edge-parity halves
        den += __shfl_xor(den, 16, 32);
        a0  += __shfl_xor(a0, 16, 32);
        a1  += __shfl_xor(a1, 16, 32);
        if (sub == 0) {
            float inv = 1.f / (den + 1e-16f);
            float v0 = a0 * inv + bias[2 * c2];
            float v1 = a1 * inv + bias[2 * c2 + 1];
            *(float2*)(out + (size_t)n * HID + 2 * c2) = make_float2(v0, v1);
            atomicAdd(&ssum[2 * c2], v0);
            atomicAdd(&ssum[2 * c2 + 1], v1);
            atomicAdd(&ssq[2 * c2], v0 * v0);
            atomicAdd(&ssq[2 * c2 + 1], v1 * v1);
        }
    }
    __syncthreads();
    if (threadIdx.x < HID) {
        atomicAdd(gsum + threadIdx.x, ssum[threadIdx.x]);
        atomicAdd(gsq + threadIdx.x, ssq[threadIdx.x]);
    }
}

// Final BN + relu + write node_embs + pool into graph_emb.
__global__ void k_bn_relu_pool(const float* __restrict__ acc, const float* __restrict__ gsum,
                               const float* __restrict__ gsq, const float* __restrict__ gamma,
                               const float* __restrict__ beta, const int* __restrict__ batch,
                               float* __restrict__ nemb, float* __restrict__ gemb) {
    int g = threadIdx.x >> 5, k = threadIdx.x & 31;
    int n = blockIdx.x * 8 + g;
    if (n >= N_NODES) return;
    const float invN = 1.f / (float)N_NODES;
    float mu = gsum[k] * invN;
    float var = gsq[k] * invN - mu * mu;
    var = fmaxf(var, 0.f);
    float scl = rsqrtf(var + BN_EPS) * gamma[k];
    float v = (acc[(size_t)n * HID + k] - mu) * scl + beta[k];
    v = fmaxf(v, 0.f);
    nemb[(size_t)n * HID + k] = v;
    atomicAdd(gemb + (size_t)batch[n] * HID + k, v);
}

__global__ void k_fc(const float* __restrict__ gemb, const float* __restrict__ W,
                     const float* __restrict__ b, float* __restrict__ out) {
    int g = blockIdx.x * blockDim.x + threadIdx.x;
    if (g >= N_GRAPHS) return;
    float a0 = b[0], a1 = b[1];
    for (int k = 0; k < HID; ++k) {
        float v = gemb[(size_t)g * HID + k];
        a0 += v * W[k * 2 + 0];
        a1 += v * W[k * 2 + 1];
    }
    out[g * 2 + 0] = a0;
    out[g * 2 + 1] = a1;
}

extern "C" void kernel_launch(void* const* d_in, const int* in_sizes, int n_in,
                              void* d_out, int out_size, void* d_ws, size_t ws_size,
                              hipStream_t stream) {
    const float* x        = (const float*)d_in[0];
    const int*   ei       = (const int*)d_in[1];  // [2, E]
    const int*   batch    = (const int*)d_in[2];
    const float* eattr    = (const float*)d_in[3];
    const float* W0       = (const float*)d_in[4];
    const float* W12      = (const float*)d_in[5];
    const float* att_src  = (const float*)d_in[6];
    const float* att_dst  = (const float*)d_in[7];
    const float* lin_edge = (const float*)d_in[8];
    const float* att_edge = (const float*)d_in[9];
    const float* bias     = (const float*)d_in[10];
    const float* bn_gamma = (const float*)d_in[11];
    const float* bn_beta  = (const float*)d_in[12];
    const float* fc_W     = (const float*)d_in[13];
    const float* fc_b     = (const float*)d_in[14];

    const int* srcA = ei;
    const int* dstA = ei + N_EDGES;

    float* out       = (float*)d_out;                       // [2000,2]
    float* node_embs = out + N_GRAPHS * N_CLASSES;          // [100000,32]
    float* graph_emb = node_embs + (size_t)N_NODES * HID;   // [2000,32]

    char* ws = (char*)d_ws;
    size_t off = 0;
    auto alloc = [&](size_t bytes) { char* p = ws + off; off += (bytes + 255) & ~(size_t)255; return p; };
    __hip_bfloat16* hT = (__hip_bfloat16*)alloc((size_t)N_NODES * HID * 2);  // bf16 h
    float* A     = (float*)alloc((size_t)N_NODES * HID * 4);   // pre-BN layer out (ping)
    int4*  pack  = (int4*)alloc((size_t)N_EDGES * 16);
    int2*  rec   = (int2*)alloc((size_t)N_EDGES * 8);
    int*   deg   = (int*)alloc((size_t)N_NODES * 4);
    int*   offs  = (int*)alloc((size_t)N_NODES * 4);
    int*   cursor= (int*)alloc((size_t)N_NODES * 4);           // becomes end-pointer
    int*   bsum  = (int*)alloc(128 * 4);
    float* asrc  = (float*)alloc((size_t)N_NODES * 4);
    float* adst  = (float*)alloc((size_t)N_NODES * 4);
    float* ce3   = (float*)alloc(12 * 4);
    float* gsum3 = (float*)alloc(3 * HID * 4);
    float* gsq3  = (float*)alloc(3 * HID * 4);
    (void)ws_size;

    const int nodeBlocks8 = (N_NODES + 7) / 8;
    const int edgeBlocks  = (N_EDGES + 255) / 256;
    const int scanBlocks  = (N_NODES + SCAN_B - 1) / SCAN_B;

    // ---- CSR build (once; reused for all 3 layers) ----
    hipMemsetAsync(deg, 0, (size_t)N_NODES * 4, stream);
    k_ce_all<<<1, 128, 0, stream>>>(lin_edge, att_edge, ce3, gsum3, gsq3);
    k_hist<<<edgeBlocks, 256, 0, stream>>>(dstA, deg);
    k_scan1<<<scanBlocks, SCAN_B, 0, stream>>>(deg, offs, bsum);
    k_scan2<<<1, 128, 0, stream>>>(bsum, scanBlocks);
    k_scan3<<<scanBlocks, SCAN_B, 0, stream>>>(offs, bsum, cursor);
    k_scatter<<<edgeBlocks, 256, 0, stream>>>(srcA, dstA, (const float4*)eattr, ce3, cursor, pack);

    // ---- Layer 0 ----
    k_linear<IN_DIM, false><<<nodeBlocks8, 256, 0, stream>>>(
        x, W0, att_src, att_dst, nullptr, nullptr, nullptr, nullptr, hT, asrc, adst);
    k_edgew<0><<<edgeBlocks, 256, 0, stream>>>(pack, asrc, adst, rec);
    k_aggr<<<nodeBlocks8, 256, 0, stream>>>(rec, offs, cursor, hT, bias, A, gsum3, gsq3);
    // ---- Layer 1 (BN0 fused) ----
    k_linear<HID, true><<<nodeBlocks8, 256, 0, stream>>>(
        A, W12, att_src + HID, att_dst + HID, gsum3, gsq3, bn_gamma, bn_beta, hT, asrc, adst);
    k_edgew<1><<<edgeBlocks, 256, 0, stream>>>(pack, asrc, adst, rec);
    k_aggr<<<nodeBlocks8, 256, 0, stream>>>(rec, offs, cursor, hT, bias + HID, A,
                                            gsum3 + HID, gsq3 + HID);
    // ---- Layer 2 (BN1 fused) ----
    k_linear<HID, true><<<nodeBlocks8, 256, 0, stream>>>(
        A, W12 + HID * HID, att_src + 2 * HID, att_dst + 2 * HID,
        gsum3 + HID, gsq3 + HID, bn_gamma + HID, bn_beta + HID, hT, asrc, adst);
    k_edgew<2><<<edgeBlocks, 256, 0, stream>>>(pack, asrc, adst, rec);
    k_aggr<<<nodeBlocks8, 256, 0, stream>>>(rec, offs, cursor, hT, bias + 2 * HID, A,
                                            gsum3 + 2 * HID, gsq3 + 2 * HID);

    // ---- BN2 + relu + node_embs + pool ----
    hipMemsetAsync(graph_emb, 0, (size_t)N_GRAPHS * HID * 4, stream);
    k_bn_relu_pool<<<nodeBlocks8, 256, 0, stream>>>(A, gsum3 + 2 * HID, gsq3 + 2 * HID,
                                                    bn_gamma + 2 * HID, bn_beta + 2 * HID,
                                                    batch, node_embs, graph_emb);
    k_fc<<<(N_GRAPHS + 255) / 256, 256, 0, stream>>>(graph_emb, fc_W, fc_b, out);
}

// Round 10
// 963.365 us; speedup vs baseline: 1.0252x; 1.0252x over previous
//
#include <hip/hip_runtime.h>
#include <hip/hip_bf16.h>
#include <math.h>

#define N_NODES   100000
#define N_EDGES   2000000
#define N_GRAPHS  2000
#define IN_DIM    7
#define EDGE_DIM  4
#define HID       32
#define N_CLASSES 2
#define NEG_SLOPE 0.2f
#define BN_EPS    1e-5f
#define SCAN_B    1024

__device__ __forceinline__ unsigned bfbits(float f) {   // fp32 -> bf16 bits (RNE)
    unsigned u = __float_as_uint(f);
    return (u + 0x7FFFu + ((u >> 16) & 1u)) >> 16;
}

// ce3[l*4+d] = sum_k We_l[d][k] * a_edge_l[k]; also zero BN accumulators.
__global__ void k_ce_all(const float* __restrict__ lin_edge, const float* __restrict__ att_edge,
                         float* __restrict__ ce3, float* __restrict__ gsum3,
                         float* __restrict__ gsq3) {
    int t = threadIdx.x;
    if (t < 12) {
        int l = t >> 2, d = t & 3;
        float s = 0.f;
        for (int k = 0; k < HID; ++k)
            s += lin_edge[(size_t)l * EDGE_DIM * HID + d * HID + k] * att_edge[l * HID + k];
        ce3[t] = s;
    }
    if (t < 3 * HID) { gsum3[t] = 0.f; gsq3[t] = 0.f; }
}

__global__ void k_hist(const int* __restrict__ dst, int* __restrict__ deg) {
    int e = blockIdx.x * blockDim.x + threadIdx.x;
    if (e < N_EDGES) atomicAdd(deg + dst[e], 1);
}

// ---- 3-phase multi-block exclusive scan of deg -> offs (+ cursor copy) ----
__global__ void k_scan1(const int* __restrict__ deg, int* __restrict__ offs,
                        int* __restrict__ bsum) {
    __shared__ int wsum[16];
    int t = threadIdx.x, lane = t & 63, w = t >> 6;
    int i = blockIdx.x * SCAN_B + t;
    int v = (i < N_NODES) ? deg[i] : 0;
    int x = v;
#pragma unroll
    for (int o = 1; o < 64; o <<= 1) { int y = __shfl_up(x, o, 64); if (lane >= o) x += y; }
    if (lane == 63) wsum[w] = x;
    __syncthreads();
    if (t < 16) {
        int s = wsum[t];
#pragma unroll
        for (int o = 1; o < 16; o <<= 1) { int y = __shfl_up(s, o, 16); if (t >= o) s += y; }
        wsum[t] = s;
    }
    __syncthreads();
    int excl = (w ? wsum[w - 1] : 0) + x - v;
    if (i < N_NODES) offs[i] = excl;
    if (t == 0) bsum[blockIdx.x] = wsum[15];
}

__global__ void k_scan2(int* __restrict__ bsum, int nb) {
    __shared__ int w0;
    int t = threadIdx.x, lane = t & 63, w = t >> 6;
    int v = (t < nb) ? bsum[t] : 0;
    int x = v;
#pragma unroll
    for (int o = 1; o < 64; o <<= 1) { int y = __shfl_up(x, o, 64); if (lane >= o) x += y; }
    if (w == 0 && lane == 63) w0 = x;
    __syncthreads();
    int excl = x - v + (w ? w0 : 0);
    if (t < nb) bsum[t] = excl;
}

__global__ void k_scan3(int* __restrict__ offs, const int* __restrict__ bsum,
                        int* __restrict__ cursor) {
    int i = blockIdx.x * SCAN_B + threadIdx.x;
    if (i < N_NODES) {
        int o = offs[i] + bsum[blockIdx.x];
        offs[i] = o;
        cursor[i] = o;
    }
}

// CSR scatter: pack[pos] = {src, dst, bf16(e0)|bf16(e1)<<16, bf16(e2)}.
__global__ void k_scatter(const int* __restrict__ src, const int* __restrict__ dst,
                          const float4* __restrict__ eattr, const float* __restrict__ ce3,
                          int* __restrict__ cursor, int4* __restrict__ pack) {
    int e = blockIdx.x * blockDim.x + threadIdx.x;
    if (e >= N_EDGES) return;
    float4 ea = eattr[e];
    float e0 = ea.x * ce3[0] + ea.y * ce3[1] + ea.z * ce3[2] + ea.w * ce3[3];
    float e1 = ea.x * ce3[4] + ea.y * ce3[5] + ea.z * ce3[6] + ea.w * ce3[7];
    float e2 = ea.x * ce3[8] + ea.y * ce3[9] + ea.z * ce3[10] + ea.w * ce3[11];
    int d = dst[e];
    int pos = atomicAdd(cursor + d, 1);
    pack[pos] = make_int4(src[e], d,
                          (int)(bfbits(e0) | (bfbits(e1) << 16)),
                          (int)bfbits(e2));
}

// h(bf16) = act(in) @ W ; asrc = h.a_src ; adst = h.a_dst (fp32 math, bf16 h storage).
// BN+relu of previous layer fused when BN. 32 lanes per node, 8 nodes per block.
template <int INDIM, bool BN>
__global__ void k_linear(const float* __restrict__ in, const float* __restrict__ W,
                         const float* __restrict__ a_src, const float* __restrict__ a_dst,
                         const float* __restrict__ gsum, const float* __restrict__ gsq,
                         const float* __restrict__ gamma, const float* __restrict__ beta,
                         __hip_bfloat16* __restrict__ h, float* __restrict__ asrc,
                         float* __restrict__ adst) {
    __shared__ float Ws[INDIM * HID];
    for (int i = threadIdx.x; i < INDIM * HID; i += blockDim.x) Ws[i] = W[i];
    __syncthreads();
    int g = threadIdx.x >> 5, k = threadIdx.x & 31;
    int n = blockIdx.x * 8 + g;
    if (n >= N_NODES) return;
    float xv;
    if (BN) {
        const float invN = 1.f / (float)N_NODES;
        float mu = gsum[k] * invN;
        float var = gsq[k] * invN - mu * mu;
        var = fmaxf(var, 0.f);
        float scl = rsqrtf(var + BN_EPS) * gamma[k];
        float v = (in[(size_t)n * INDIM + k] - mu) * scl + beta[k];
        xv = fmaxf(v, 0.f);
    } else {
        xv = (k < INDIM) ? in[(size_t)n * INDIM + k] : 0.f;
    }
    float acc = 0.f;
#pragma unroll
    for (int d = 0; d < INDIM; ++d) acc += __shfl(xv, d, 32) * Ws[d * HID + k];
    h[(size_t)n * HID + k] = __float2bfloat16(acc);
    float vs = acc * a_src[k];
    float vd = acc * a_dst[k];
#pragma unroll
    for (int m = 16; m > 0; m >>= 1) {
        vs += __shfl_xor(vs, m, 32);
        vd += __shfl_xor(vd, m, 32);
    }
    if (k == 0) { asrc[n] = vs; adst[n] = vd; }
}

// Edge-parallel full-weight precompute: rec[e] = {src, w = exp(leaky(asrc+adst+edot))}.
// Scores are O(1) (inputs ~N(0,1), weights x0.1): exp without max-subtraction equals the
// reference segment-softmax algebraically (exp(s-m)/sum == exp(s)/sum), numerically safe.
template <int L>
__global__ void k_edgew(const int4* __restrict__ pack, const float* __restrict__ asrc,
                        const float* __restrict__ adst, int2* __restrict__ rec) {
    int e = blockIdx.x * blockDim.x + threadIdx.x;
    if (e >= N_EDGES) return;
    int4 pk = pack[e];
    unsigned z = (unsigned)pk.z;
    float edot;
    if (L == 0)      edot = __uint_as_float((z & 0xFFFFu) << 16);
    else if (L == 1) edot = __uint_as_float(z & 0xFFFF0000u);
    else             edot = __uint_as_float(((unsigned)pk.w & 0xFFFFu) << 16);
    float sc = asrc[pk.x] + adst[pk.y] + edot;
    sc = fmaxf(sc, NEG_SLOPE * sc);       // leaky-relu (slope<1)
    float w = __expf(sc);
    rec[e] = make_int2(pk.x, __float_as_int(w));
}

// Per-node weighted-sum aggregation. 32 lanes/node, 8 nodes/block.
// Lane split: sub = lane>>4 (edge-slot parity), c2 = lane&15 (channel pair 2c2,2c2+1).
// 16-edge batches: 8 int2 rec loads then 8 packed-u32 h loads ALL in flight before any
// consume -> 2x the outstanding random lines of round 8 (MLP/Little's-law attack).
__global__ void k_aggr(const int2* __restrict__ rec, const int* __restrict__ offs,
                       const int* __restrict__ endp, const __hip_bfloat16* __restrict__ hb,
                       const float* __restrict__ bias, float* __restrict__ out,
                       float* __restrict__ gsum, float* __restrict__ gsq) {
    __shared__ float ssum[HID], ssq[HID];
    if (threadIdx.x < HID) { ssum[threadIdx.x] = 0.f; ssq[threadIdx.x] = 0.f; }
    __syncthreads();
    int g = threadIdx.x >> 5;
    int lane = threadIdx.x & 31;
    int sub = lane >> 4;      // which edge of a slot pair
    int c2 = lane & 15;       // channel pair index
    int n = blockIdx.x * 8 + g;
    if (n < N_NODES) {
        int pbeg = offs[n], en = endp[n];
        float den = 0.f, a0 = 0.f, a1 = 0.f;
        for (int p = pbeg; p < en; p += 16) {
            int2 rc[8];
            unsigned hw[8];
#pragma unroll
            for (int m = 0; m < 8; ++m) {
                int q = p + 2 * m + sub;
                q = q < en ? q : en - 1;   // clamp; weight masked below
                rc[m] = rec[q];
            }
#pragma unroll
            for (int m = 0; m < 8; ++m)
                hw[m] = *(const unsigned*)(hb + (size_t)rc[m].x * HID + 2 * c2);
#pragma unroll
            for (int m = 0; m < 8; ++m) {
                float w = (p + 2 * m + sub < en) ? __int_as_float(rc[m].y) : 0.f;
                den += w;
                float lo = __uint_as_float((hw[m] & 0xFFFFu) << 16);
                float hi = __uint_as_float(hw[m] & 0xFFFF0000u);
                a0 = fmaf(w, lo, a0);
                a1 = fmaf(w, hi, a1);
            }
        }
        // combine the two edge-parity halves
        den += __shfl_xor(den, 16, 32);
        a0  += __shfl_xor(a0, 16, 32);
        a1  += __shfl_xor(a1, 16, 32);
        if (sub == 0) {
            float inv = 1.f / (den + 1e-16f);
            float v0 = a0 * inv + bias[2 * c2];
            float v1 = a1 * inv + bias[2 * c2 + 1];
            *(float2*)(out + (size_t)n * HID + 2 * c2) = make_float2(v0, v1);
            atomicAdd(&ssum[2 * c2], v0);
            atomicAdd(&ssum[2 * c2 + 1], v1);
            atomicAdd(&ssq[2 * c2], v0 * v0);
            atomicAdd(&ssq[2 * c2 + 1], v1 * v1);
        }
    }
    __syncthreads();
    if (threadIdx.x < HID) {
        atomicAdd(gsum + threadIdx.x, ssum[threadIdx.x]);
        atomicAdd(gsq + threadIdx.x, ssq[threadIdx.x]);
    }
}

// Final BN + relu + write node_embs + pool into graph_emb.
__global__ void k_bn_relu_pool(const float* __restrict__ acc, const float* __restrict__ gsum,
                               const float* __restrict__ gsq, const float* __restrict__ gamma,
                               const float* __restrict__ beta, const int* __restrict__ batch,
                               float* __restrict__ nemb, float* __restrict__ gemb) {
    int g = threadIdx.x >> 5, k = threadIdx.x & 31;
    int n = blockIdx.x * 8 + g;
    if (n >= N_NODES) return;
    const float invN = 1.f / (float)N_NODES;
    float mu = gsum[k] * invN;
    float var = gsq[k] * invN - mu * mu;
    var = fmaxf(var, 0.f);
    float scl = rsqrtf(var + BN_EPS) * gamma[k];
    float v = (acc[(size_t)n * HID + k] - mu) * scl + beta[k];
    v = fmaxf(v, 0.f);
    nemb[(size_t)n * HID + k] = v;
    atomicAdd(gemb + (size_t)batch[n] * HID + k, v);
}

__global__ void k_fc(const float* __restrict__ gemb, const float* __restrict__ W,
                     const float* __restrict__ b, float* __restrict__ out) {
    int g = blockIdx.x * blockDim.x + threadIdx.x;
    if (g >= N_GRAPHS) return;
    float a0 = b[0], a1 = b[1];
    for (int k = 0; k < HID; ++k) {
        float v = gemb[(size_t)g * HID + k];
        a0 += v * W[k * 2 + 0];
        a1 += v * W[k * 2 + 1];
    }
    out[g * 2 + 0] = a0;
    out[g * 2 + 1] = a1;
}

extern "C" void kernel_launch(void* const* d_in, const int* in_sizes, int n_in,
                              void* d_out, int out_size, void* d_ws, size_t ws_size,
                              hipStream_t stream) {
    const float* x        = (const float*)d_in[0];
    const int*   ei       = (const int*)d_in[1];  // [2, E]
    const int*   batch    = (const int*)d_in[2];
    const float* eattr    = (const float*)d_in[3];
    const float* W0       = (const float*)d_in[4];
    const float* W12      = (const float*)d_in[5];
    const float* att_src  = (const float*)d_in[6];
    const float* att_dst  = (const float*)d_in[7];
    const float* lin_edge = (const float*)d_in[8];
    const float* att_edge = (const float*)d_in[9];
    const float* bias     = (const float*)d_in[10];
    const float* bn_gamma = (const float*)d_in[11];
    const float* bn_beta  = (const float*)d_in[12];
    const float* fc_W     = (const float*)d_in[13];
    const float* fc_b     = (const float*)d_in[14];

    const int* srcA = ei;
    const int* dstA = ei + N_EDGES;

    float* out       = (float*)d_out;                       // [2000,2]
    float* node_embs = out + N_GRAPHS * N_CLASSES;          // [100000,32]
    float* graph_emb = node_embs + (size_t)N_NODES * HID;   // [2000,32]

    char* ws = (char*)d_ws;
    size_t off = 0;
    auto alloc = [&](size_t bytes) { char* p = ws + off; off += (bytes + 255) & ~(size_t)255; return p; };
    __hip_bfloat16* hT = (__hip_bfloat16*)alloc((size_t)N_NODES * HID * 2);  // bf16 h
    float* A     = (float*)alloc((size_t)N_NODES * HID * 4);   // pre-BN layer out (ping)
    int4*  pack  = (int4*)alloc((size_t)N_EDGES * 16);
    int2*  rec   = (int2*)alloc((size_t)N_EDGES * 8);
    int*   deg   = (int*)alloc((size_t)N_NODES * 4);
    int*   offs  = (int*)alloc((size_t)N_NODES * 4);
    int*   cursor= (int*)alloc((size_t)N_NODES * 4);           // becomes end-pointer
    int*   bsum  = (int*)alloc(128 * 4);
    float* asrc  = (float*)alloc((size_t)N_NODES * 4);
    float* adst  = (float*)alloc((size_t)N_NODES * 4);
    float* ce3   = (float*)alloc(12 * 4);
    float* gsum3 = (float*)alloc(3 * HID * 4);
    float* gsq3  = (float*)alloc(3 * HID * 4);
    (void)ws_size;

    const int nodeBlocks8 = (N_NODES + 7) / 8;
    const int edgeBlocks  = (N_EDGES + 255) / 256;
    const int scanBlocks  = (N_NODES + SCAN_B - 1) / SCAN_B;

    // ---- CSR build (once; reused for all 3 layers) ----
    hipMemsetAsync(deg, 0, (size_t)N_NODES * 4, stream);
    k_ce_all<<<1, 128, 0, stream>>>(lin_edge, att_edge, ce3, gsum3, gsq3);
    k_hist<<<edgeBlocks, 256, 0, stream>>>(dstA, deg);
    k_scan1<<<scanBlocks, SCAN_B, 0, stream>>>(deg, offs, bsum);
    k_scan2<<<1, 128, 0, stream>>>(bsum, scanBlocks);
    k_scan3<<<scanBlocks, SCAN_B, 0, stream>>>(offs, bsum, cursor);
    k_scatter<<<edgeBlocks, 256, 0, stream>>>(srcA, dstA, (const float4*)eattr, ce3, cursor, pack);

    // ---- Layer 0 ----
    k_linear<IN_DIM, false><<<nodeBlocks8, 256, 0, stream>>>(
        x, W0, att_src, att_dst, nullptr, nullptr, nullptr, nullptr, hT, asrc, adst);
    k_edgew<0><<<edgeBlocks, 256, 0, stream>>>(pack, asrc, adst, rec);
    k_aggr<<<nodeBlocks8, 256, 0, stream>>>(rec, offs, cursor, hT, bias, A, gsum3, gsq3);
    // ---- Layer 1 (BN0 fused) ----
    k_linear<HID, true><<<nodeBlocks8, 256, 0, stream>>>(
        A, W12, att_src + HID, att_dst + HID, gsum3, gsq3, bn_gamma, bn_beta, hT, asrc, adst);
    k_edgew<1><<<edgeBlocks, 256, 0, stream>>>(pack, asrc, adst, rec);
    k_aggr<<<nodeBlocks8, 256, 0, stream>>>(rec, offs, cursor, hT, bias + HID, A,
                                            gsum3 + HID, gsq3 + HID);
    // ---- Layer 2 (BN1 fused) ----
    k_linear<HID, true><<<nodeBlocks8, 256, 0, stream>>>(
        A, W12 + HID * HID, att_src + 2 * HID, att_dst + 2 * HID,
        gsum3 + HID, gsq3 + HID, bn_gamma + HID, bn_beta + HID, hT, asrc, adst);
    k_edgew<2><<<edgeBlocks, 256, 0, stream>>>(pack, asrc, adst, rec);
    k_aggr<<<nodeBlocks8, 256, 0, stream>>>(rec, offs, cursor, hT, bias + 2 * HID, A,
                                            gsum3 + 2 * HID, gsq3 + 2 * HID);

    // ---- BN2 + relu + node_embs + pool ----
    hipMemsetAsync(graph_emb, 0, (size_t)N_GRAPHS * HID * 4, stream);
    k_bn_relu_pool<<<nodeBlocks8, 256, 0, stream>>>(A, gsum3 + 2 * HID, gsq3 + 2 * HID,
                                                    bn_gamma + 2 * HID, bn_beta + 2 * HID,
                                                    batch, node_embs, graph_emb);
    k_fc<<<(N_GRAPHS + 255) / 256, 256, 0, stream>>>(graph_emb, fc_W, fc_b, out);
}

// Round 11
// 930.354 us; speedup vs baseline: 1.0616x; 1.0355x over previous
//
#include <hip/hip_runtime.h>
#include <hip/hip_bf16.h>
#include <math.h>

#define N_NODES   100000
#define N_EDGES   2000000
#define N_GRAPHS  2000
#define IN_DIM    7
#define EDGE_DIM  4
#define HID       32
#define N_CLASSES 2
#define NEG_SLOPE 0.2f
#define BN_EPS    1e-5f
#define SCAN_B    1024

__device__ __forceinline__ unsigned bfbits(float f) {   // fp32 -> bf16 bits (RNE)
    unsigned u = __float_as_uint(f);
    return (u + 0x7FFFu + ((u >> 16) & 1u)) >> 16;
}

// ce3[l*4+d] = sum_k We_l[d][k] * a_edge_l[k]; also zero BN accumulators.
__global__ void k_ce_all(const float* __restrict__ lin_edge, const float* __restrict__ att_edge,
                         float* __restrict__ ce3, float* __restrict__ gsum3,
                         float* __restrict__ gsq3) {
    int t = threadIdx.x;
    if (t < 12) {
        int l = t >> 2, d = t & 3;
        float s = 0.f;
        for (int k = 0; k < HID; ++k)
            s += lin_edge[(size_t)l * EDGE_DIM * HID + d * HID + k] * att_edge[l * HID + k];
        ce3[t] = s;
    }
    if (t < 3 * HID) { gsum3[t] = 0.f; gsq3[t] = 0.f; }
}

__global__ void k_hist(const int* __restrict__ dst, int* __restrict__ deg) {
    int e = blockIdx.x * blockDim.x + threadIdx.x;
    if (e < N_EDGES) atomicAdd(deg + dst[e], 1);
}

// ---- 3-phase multi-block exclusive scan of deg -> offs (+ cursor copy) ----
__global__ void k_scan1(const int* __restrict__ deg, int* __restrict__ offs,
                        int* __restrict__ bsum) {
    __shared__ int wsum[16];
    int t = threadIdx.x, lane = t & 63, w = t >> 6;
    int i = blockIdx.x * SCAN_B + t;
    int v = (i < N_NODES) ? deg[i] : 0;
    int x = v;
#pragma unroll
    for (int o = 1; o < 64; o <<= 1) { int y = __shfl_up(x, o, 64); if (lane >= o) x += y; }
    if (lane == 63) wsum[w] = x;
    __syncthreads();
    if (t < 16) {
        int s = wsum[t];
#pragma unroll
        for (int o = 1; o < 16; o <<= 1) { int y = __shfl_up(s, o, 16); if (t >= o) s += y; }
        wsum[t] = s;
    }
    __syncthreads();
    int excl = (w ? wsum[w - 1] : 0) + x - v;
    if (i < N_NODES) offs[i] = excl;
    if (t == 0) bsum[blockIdx.x] = wsum[15];
}

__global__ void k_scan2(int* __restrict__ bsum, int nb) {
    __shared__ int w0;
    int t = threadIdx.x, lane = t & 63, w = t >> 6;
    int v = (t < nb) ? bsum[t] : 0;
    int x = v;
#pragma unroll
    for (int o = 1; o < 64; o <<= 1) { int y = __shfl_up(x, o, 64); if (lane >= o) x += y; }
    if (w == 0 && lane == 63) w0 = x;
    __syncthreads();
    int excl = x - v + (w ? w0 : 0);
    if (t < nb) bsum[t] = excl;
}

__global__ void k_scan3(int* __restrict__ offs, const int* __restrict__ bsum,
                        int* __restrict__ cursor) {
    int i = blockIdx.x * SCAN_B + threadIdx.x;
    if (i < N_NODES) {
        int o = offs[i] + bsum[blockIdx.x];
        offs[i] = o;
        cursor[i] = o;
    }
}

// CSR scatter: pack[pos] = {src, bf16(e0)|bf16(e1)<<16, bf16(e2), 0}.
__global__ void k_scatter(const int* __restrict__ src, const int* __restrict__ dst,
                          const float4* __restrict__ eattr, const float* __restrict__ ce3,
                          int* __restrict__ cursor, int4* __restrict__ pack) {
    int e = blockIdx.x * blockDim.x + threadIdx.x;
    if (e >= N_EDGES) return;
    float4 ea = eattr[e];
    float e0 = ea.x * ce3[0] + ea.y * ce3[1] + ea.z * ce3[2] + ea.w * ce3[3];
    float e1 = ea.x * ce3[4] + ea.y * ce3[5] + ea.z * ce3[6] + ea.w * ce3[7];
    float e2 = ea.x * ce3[8] + ea.y * ce3[9] + ea.z * ce3[10] + ea.w * ce3[11];
    int d = dst[e];
    int pos = atomicAdd(cursor + d, 1);
    pack[pos] = make_int4(src[e],
                          (int)(bfbits(e0) | (bfbits(e1) << 16)),
                          (int)bfbits(e2), 0);
}

// h(bf16) = act(in) @ W ; asrc = h.a_src ; adst = h.a_dst (fp32 math, bf16 h storage).
// BN+relu of previous layer fused when BN. 32 lanes per node, 8 nodes per block.
template <int INDIM, bool BN>
__global__ void k_linear(const float* __restrict__ in, const float* __restrict__ W,
                         const float* __restrict__ a_src, const float* __restrict__ a_dst,
                         const float* __restrict__ gsum, const float* __restrict__ gsq,
                         const float* __restrict__ gamma, const float* __restrict__ beta,
                         __hip_bfloat16* __restrict__ h, float* __restrict__ asrc,
                         float* __restrict__ adst) {
    __shared__ float Ws[INDIM * HID];
    for (int i = threadIdx.x; i < INDIM * HID; i += blockDim.x) Ws[i] = W[i];
    __syncthreads();
    int g = threadIdx.x >> 5, k = threadIdx.x & 31;
    int n = blockIdx.x * 8 + g;
    if (n >= N_NODES) return;
    float xv;
    if (BN) {
        const float invN = 1.f / (float)N_NODES;
        float mu = gsum[k] * invN;
        float var = gsq[k] * invN - mu * mu;
        var = fmaxf(var, 0.f);
        float scl = rsqrtf(var + BN_EPS) * gamma[k];
        float v = (in[(size_t)n * INDIM + k] - mu) * scl + beta[k];
        xv = fmaxf(v, 0.f);
    } else {
        xv = (k < INDIM) ? in[(size_t)n * INDIM + k] : 0.f;
    }
    float acc = 0.f;
#pragma unroll
    for (int d = 0; d < INDIM; ++d) acc += __shfl(xv, d, 32) * Ws[d * HID + k];
    h[(size_t)n * HID + k] = __float2bfloat16(acc);
    float vs = acc * a_src[k];
    float vd = acc * a_dst[k];
#pragma unroll
    for (int m = 16; m > 0; m >>= 1) {
        vs += __shfl_xor(vs, m, 32);
        vd += __shfl_xor(vd, m, 32);
    }
    if (k == 0) { asrc[n] = vs; adst[n] = vd; }
}

// Fused per-node softmax-weighted aggregation over CSR incoming edges.
// Scores are O(1) (inputs ~N(0,1), weights x0.1): exp without max-subtraction equals the
// reference segment-softmax algebraically (exp(s-m)/sum == exp(s)/sum), numerically safe.
// Weight compute is inline (r7 evidence: in-loop asrc gather + exp costs nothing vs the
// LLC-random-gather floor; the separate k_edgew pass was pure overhead).
// Lane split: sub = lane>>4 (edge parity), c2 = lane&15 (channel pair). 16-edge batches:
// 8 pack int4 + 8 asrc + 8 packed-u32 h loads per batch = 1.5 mem-inst/edge.
template <int L>
__global__ void k_aggr(const int4* __restrict__ pack, const int* __restrict__ offs,
                       const int* __restrict__ endp, const __hip_bfloat16* __restrict__ hb,
                       const float* __restrict__ asrc, const float* __restrict__ adst,
                       const float* __restrict__ bias, float* __restrict__ out,
                       float* __restrict__ gsum, float* __restrict__ gsq) {
    __shared__ float ssum[HID], ssq[HID];
    if (threadIdx.x < HID) { ssum[threadIdx.x] = 0.f; ssq[threadIdx.x] = 0.f; }
    __syncthreads();
    int g = threadIdx.x >> 5;
    int lane = threadIdx.x & 31;
    int sub = lane >> 4;      // which edge of a slot pair
    int c2 = lane & 15;       // channel pair index
    int n = blockIdx.x * 8 + g;
    if (n < N_NODES) {
        int pbeg = offs[n], en = endp[n];
        float ad = adst[n];
        float den = 0.f, a0 = 0.f, a1 = 0.f;
        for (int p = pbeg; p < en; p += 16) {
            int4 pk[8];
            float as[8];
            unsigned hw[8];
#pragma unroll
            for (int m = 0; m < 8; ++m) {
                int q = p + 2 * m + sub;
                q = q < en ? q : en - 1;   // clamp; weight masked below
                pk[m] = pack[q];
            }
#pragma unroll
            for (int m = 0; m < 8; ++m) as[m] = asrc[pk[m].x];
#pragma unroll
            for (int m = 0; m < 8; ++m)
                hw[m] = *(const unsigned*)(hb + (size_t)pk[m].x * HID + 2 * c2);
#pragma unroll
            for (int m = 0; m < 8; ++m) {
                unsigned z = (unsigned)pk[m].y;
                float edot;
                if (L == 0)      edot = __uint_as_float((z & 0xFFFFu) << 16);
                else if (L == 1) edot = __uint_as_float(z & 0xFFFF0000u);
                else             edot = __uint_as_float(((unsigned)pk[m].z & 0xFFFFu) << 16);
                float sc = as[m] + ad + edot;
                sc = fmaxf(sc, NEG_SLOPE * sc);   // leaky-relu (slope<1)
                float w = (p + 2 * m + sub < en) ? __expf(sc) : 0.f;
                den += w;
                float lo = __uint_as_float((hw[m] & 0xFFFFu) << 16);
                float hi = __uint_as_float(hw[m] & 0xFFFF0000u);
                a0 = fmaf(w, lo, a0);
                a1 = fmaf(w, hi, a1);
            }
        }
        // combine the two edge-parity halves
        den += __shfl_xor(den, 16, 32);
        a0  += __shfl_xor(a0, 16, 32);
        a1  += __shfl_xor(a1, 16, 32);
        if (sub == 0) {
            float inv = 1.f / (den + 1e-16f);
            float v0 = a0 * inv + bias[2 * c2];
            float v1 = a1 * inv + bias[2 * c2 + 1];
            *(float2*)(out + (size_t)n * HID + 2 * c2) = make_float2(v0, v1);
            atomicAdd(&ssum[2 * c2], v0);
            atomicAdd(&ssum[2 * c2 + 1], v1);
            atomicAdd(&ssq[2 * c2], v0 * v0);
            atomicAdd(&ssq[2 * c2 + 1], v1 * v1);
        }
    }
    __syncthreads();
    if (threadIdx.x < HID) {
        atomicAdd(gsum + threadIdx.x, ssum[threadIdx.x]);
        atomicAdd(gsq + threadIdx.x, ssq[threadIdx.x]);
    }
}

// Final BN + relu + write node_embs + pool into graph_emb.
__global__ void k_bn_relu_pool(const float* __restrict__ acc, const float* __restrict__ gsum,
                               const float* __restrict__ gsq, const float* __restrict__ gamma,
                               const float* __restrict__ beta, const int* __restrict__ batch,
                               float* __restrict__ nemb, float* __restrict__ gemb) {
    int g = threadIdx.x >> 5, k = threadIdx.x & 31;
    int n = blockIdx.x * 8 + g;
    if (n >= N_NODES) return;
    const float invN = 1.f / (float)N_NODES;
    float mu = gsum[k] * invN;
    float var = gsq[k] * invN - mu * mu;
    var = fmaxf(var, 0.f);
    float scl = rsqrtf(var + BN_EPS) * gamma[k];
    float v = (acc[(size_t)n * HID + k] - mu) * scl + beta[k];
    v = fmaxf(v, 0.f);
    nemb[(size_t)n * HID + k] = v;
    atomicAdd(gemb + (size_t)batch[n] * HID + k, v);
}

__global__ void k_fc(const float* __restrict__ gemb, const float* __restrict__ W,
                     const float* __restrict__ b, float* __restrict__ out) {
    int g = blockIdx.x * blockDim.x + threadIdx.x;
    if (g >= N_GRAPHS) return;
    float a0 = b[0], a1 = b[1];
    for (int k = 0; k < HID; ++k) {
        float v = gemb[(size_t)g * HID + k];
        a0 += v * W[k * 2 + 0];
        a1 += v * W[k * 2 + 1];
    }
    out[g * 2 + 0] = a0;
    out[g * 2 + 1] = a1;
}

extern "C" void kernel_launch(void* const* d_in, const int* in_sizes, int n_in,
                              void* d_out, int out_size, void* d_ws, size_t ws_size,
                              hipStream_t stream) {
    const float* x        = (const float*)d_in[0];
    const int*   ei       = (const int*)d_in[1];  // [2, E]
    const int*   batch    = (const int*)d_in[2];
    const float* eattr    = (const float*)d_in[3];
    const float* W0       = (const float*)d_in[4];
    const float* W12      = (const float*)d_in[5];
    const float* att_src  = (const float*)d_in[6];
    const float* att_dst  = (const float*)d_in[7];
    const float* lin_edge = (const float*)d_in[8];
    const float* att_edge = (const float*)d_in[9];
    const float* bias     = (const float*)d_in[10];
    const float* bn_gamma = (const float*)d_in[11];
    const float* bn_beta  = (const float*)d_in[12];
    const float* fc_W     = (const float*)d_in[13];
    const float* fc_b     = (const float*)d_in[14];

    const int* srcA = ei;
    const int* dstA = ei + N_EDGES;

    float* out       = (float*)d_out;                       // [2000,2]
    float* node_embs = out + N_GRAPHS * N_CLASSES;          // [100000,32]
    float* graph_emb = node_embs + (size_t)N_NODES * HID;   // [2000,32]

    char* ws = (char*)d_ws;
    size_t off = 0;
    auto alloc = [&](size_t bytes) { char* p = ws + off; off += (bytes + 255) & ~(size_t)255; return p; };
    __hip_bfloat16* hT = (__hip_bfloat16*)alloc((size_t)N_NODES * HID * 2);  // bf16 h
    float* A     = (float*)alloc((size_t)N_NODES * HID * 4);   // pre-BN layer out (ping)
    int4*  pack  = (int4*)alloc((size_t)N_EDGES * 16);
    int*   deg   = (int*)alloc((size_t)N_NODES * 4);
    int*   offs  = (int*)alloc((size_t)N_NODES * 4);
    int*   cursor= (int*)alloc((size_t)N_NODES * 4);           // becomes end-pointer
    int*   bsum  = (int*)alloc(128 * 4);
    float* asrc  = (float*)alloc((size_t)N_NODES * 4);
    float* adst  = (float*)alloc((size_t)N_NODES * 4);
    float* ce3   = (float*)alloc(12 * 4);
    float* gsum3 = (float*)alloc(3 * HID * 4);
    float* gsq3  = (float*)alloc(3 * HID * 4);
    (void)ws_size;

    const int nodeBlocks8 = (N_NODES + 7) / 8;
    const int edgeBlocks  = (N_EDGES + 255) / 256;
    const int scanBlocks  = (N_NODES + SCAN_B - 1) / SCAN_B;

    // ---- CSR build (once; reused for all 3 layers) ----
    hipMemsetAsync(deg, 0, (size_t)N_NODES * 4, stream);
    k_ce_all<<<1, 128, 0, stream>>>(lin_edge, att_edge, ce3, gsum3, gsq3);
    k_hist<<<edgeBlocks, 256, 0, stream>>>(dstA, deg);
    k_scan1<<<scanBlocks, SCAN_B, 0, stream>>>(deg, offs, bsum);
    k_scan2<<<1, 128, 0, stream>>>(bsum, scanBlocks);
    k_scan3<<<scanBlocks, SCAN_B, 0, stream>>>(offs, bsum, cursor);
    k_scatter<<<edgeBlocks, 256, 0, stream>>>(srcA, dstA, (const float4*)eattr, ce3, cursor, pack);

    // ---- Layer 0 ----
    k_linear<IN_DIM, false><<<nodeBlocks8, 256, 0, stream>>>(
        x, W0, att_src, att_dst, nullptr, nullptr, nullptr, nullptr, hT, asrc, adst);
    k_aggr<0><<<nodeBlocks8, 256, 0, stream>>>(pack, offs, cursor, hT, asrc, adst,
                                               bias, A, gsum3, gsq3);
    // ---- Layer 1 (BN0 fused) ----
    k_linear<HID, true><<<nodeBlocks8, 256, 0, stream>>>(
        A, W12, att_src + HID, att_dst + HID, gsum3, gsq3, bn_gamma, bn_beta, hT, asrc, adst);
    k_aggr<1><<<nodeBlocks8, 256, 0, stream>>>(pack, offs, cursor, hT, asrc, adst,
                                               bias + HID, A, gsum3 + HID, gsq3 + HID);
    // ---- Layer 2 (BN1 fused) ----
    k_linear<HID, true><<<nodeBlocks8, 256, 0, stream>>>(
        A, W12 + HID * HID, att_src + 2 * HID, att_dst + 2 * HID,
        gsum3 + HID, gsq3 + HID, bn_gamma + HID, bn_beta + HID, hT, asrc, adst);
    k_aggr<2><<<nodeBlocks8, 256, 0, stream>>>(pack, offs, cursor, hT, asrc, adst,
                                               bias + 2 * HID, A, gsum3 + 2 * HID, gsq3 + 2 * HID);

    // ---- BN2 + relu + node_embs + pool ----
    hipMemsetAsync(graph_emb, 0, (size_t)N_GRAPHS * HID * 4, stream);
    k_bn_relu_pool<<<nodeBlocks8, 256, 0, stream>>>(A, gsum3 + 2 * HID, gsq3 + 2 * HID,
                                                    bn_gamma + 2 * HID, bn_beta + 2 * HID,
                                                    batch, node_embs, graph_emb);
    k_fc<<<(N_GRAPHS + 255) / 256, 256, 0, stream>>>(graph_emb, fc_W, fc_b, out);
}